// Round 4
// baseline (773.642 us; speedup 1.0000x reference)
//
#include <hip/hip_runtime.h>

typedef _Float16 half8 __attribute__((ext_vector_type(8)));
typedef float floatx4 __attribute__((ext_vector_type(4)));

#define CIN 32
#define COUT 32
#define KOFF 27
#define EPSV 1e-5f

// ---------------------------------------------------------------------------
// ws layout:
//   [0, N*32*2)            feats16 (f16 copy of feats)      64 MB  (L3-resident)
//   [+, +55296)            Wpack: B-fragments, f16          55 KB
//   [align 512, +768)      stats: sum[32], sumsq[32], flag
//   [align 256, +N*27*4)   nbrT: transposed idx|mask<<31    108 MB (NT streams)
// y (pre-BN conv output, fp32) lives in d_out: NT-stored by conv, NT r/w by
// bn_apply — y traffic must NOT evict feats16 from L3 (round-3 FETCH showed
// 670 MB of gather re-fetch caused by temporal y stores thrashing L3).
// ---------------------------------------------------------------------------

// blocks 0..26: pack W fragments; block 27: detect mask dtype.
__global__ void setup_k(const float* __restrict__ W, _Float16* __restrict__ wp,
                        const unsigned char* __restrict__ m,
                        int* __restrict__ flag) {
  if (blockIdx.x < KOFF) {
    int ko = blockIdx.x;
    int h = threadIdx.x >> 6;
    int lane = threadIdx.x & 63;
    int col = lane & 15, quad = lane >> 4;
    half8 p;
#pragma unroll
    for (int j = 0; j < 8; ++j) {
      int k = quad * 8 + j;
      p[j] = (_Float16)W[(ko * CIN + k) * COUT + h * 16 + col];
    }
    *(half8*)(wp + ((size_t)(ko * 2 + h) * 64 + lane) * 8) = p;
  } else {
    int tid = threadIdx.x;
    int any = 0;
    for (int i = tid; i < 4096; i += 128) {
      if ((i & 3) != 0 && m[i] != 0) any = 1;
    }
    if (any) atomicOr(flag, 1);
  }
}

// blocks [0,cvtBlocks): feats fp32->f16.  rest: transpose neighbor map.
__global__ void prep_k(const float* __restrict__ feats,
                       _Float16* __restrict__ f16, int total8,
                       const int* __restrict__ nidx,
                       const unsigned char* __restrict__ nmask,
                       const int* __restrict__ flagp,
                       int* __restrict__ nbrT, int N, int cvtBlocks) {
  __shared__ int lds[256 * 29];
  int tid = threadIdx.x;
  if ((int)blockIdx.x < cvtBlocks) {
    int t = blockIdx.x * 256 + tid;
    if (t >= total8) return;
    const floatx4* in4 = (const floatx4*)feats;
    floatx4 a = __builtin_nontemporal_load(&in4[t * 2]);
    floatx4 b = __builtin_nontemporal_load(&in4[t * 2 + 1]);
    half8 h;
    h[0] = (_Float16)a[0]; h[1] = (_Float16)a[1];
    h[2] = (_Float16)a[2]; h[3] = (_Float16)a[3];
    h[4] = (_Float16)b[0]; h[5] = (_Float16)b[1];
    h[6] = (_Float16)b[2]; h[7] = (_Float16)b[3];
    *(half8*)(f16 + (size_t)t * 8) = h;  // temporal: keep L3-resident
  } else {
    bool bytemode = (*flagp != 0);
    const int* nmask32 = (const int*)nmask;
    int tileBase = (blockIdx.x - cvtBlocks) * 256;
    int nvox = min(256, N - tileBase);
    if (nvox <= 0) return;
    int total = nvox * KOFF;
    for (int p = tid; p < total; p += 256) {
      int voxl = p / KOFF;
      int ko = p - voxl * KOFF;
      int g = tileBase * KOFF + p;
      int idx = __builtin_nontemporal_load(&nidx[g]);
      int mk = bytemode ? (int)__builtin_nontemporal_load(&nmask[g])
                        : __builtin_nontemporal_load(&nmask32[g]);
      lds[voxl * 29 + ko] = (idx & 0x7FFFFFFF) | (mk ? (int)0x80000000 : 0);
    }
    __syncthreads();
    if (tid < nvox) {
#pragma unroll
      for (int ko = 0; ko < KOFF; ++ko) {
        __builtin_nontemporal_store(lds[tid * 29 + ko],
                                    &nbrT[(size_t)ko * N + tileBase + tid]);
      }
    }
  }
}

__launch_bounds__(256)
__global__ void conv_mfma_t(const _Float16* __restrict__ f16,
                            const _Float16* __restrict__ wp,
                            const int* __restrict__ nbrT,
                            float* __restrict__ y,
                            float* __restrict__ stats, int N) {
  __shared__ float smS[4 * 32];
  __shared__ float smQ[4 * 32];
  int wave = threadIdx.x >> 6;
  int lane = threadIdx.x & 63;
  int base = (blockIdx.x * 4 + wave) * 64;
  bool active = base < N;
  int col = lane & 15, quad = lane >> 4;
  const half8* wfrag = (const half8*)wp;

  floatx4 acc[4][2];
#pragma unroll
  for (int t = 0; t < 4; ++t)
#pragma unroll
    for (int h = 0; h < 2; ++h) {
      acc[t][h][0] = 0.f; acc[t][h][1] = 0.f;
      acc[t][h][2] = 0.f; acc[t][h][3] = 0.f;
    }

  if (active) {
    // round-2 structure: let the unroller batch 12 nbrT + 12 gathers per group
#pragma unroll 3
    for (int ko = 0; ko < KOFF; ++ko) {
      half8 b0 = wfrag[(size_t)(ko * 2 + 0) * 64 + lane];
      half8 b1 = wfrag[(size_t)(ko * 2 + 1) * 64 + lane];
      const int* row = nbrT + (size_t)ko * N + base;
#pragma unroll
      for (int t = 0; t < 4; ++t) {
        int v = __builtin_nontemporal_load(&row[t * 16 + col]);
        half8 a;
#pragma unroll
        for (int j = 0; j < 8; ++j) a[j] = (_Float16)0.f;
        if (v < 0) {  // bit31 == valid
          int nb = v & 0x7FFFFFFF;
          a = *(const half8*)(f16 + (size_t)nb * CIN + quad * 8);
        }
        acc[t][0] = __builtin_amdgcn_mfma_f32_16x16x32_f16(a, b0, acc[t][0], 0, 0, 0);
        acc[t][1] = __builtin_amdgcn_mfma_f32_16x16x32_f16(a, b1, acc[t][1], 0, 0, 0);
      }
    }
  }

  // ---- epilogue: NT y store + fused BN partial sums ----
  float s0 = 0.f, s1 = 0.f, q0 = 0.f, q1 = 0.f;
  if (active) {
#pragma unroll
    for (int t = 0; t < 4; ++t) {
#pragma unroll
      for (int h = 0; h < 2; ++h) {
        floatx4 c = acc[t][h];
        int co = h * 16 + col;
#pragma unroll
        for (int r = 0; r < 4; ++r) {
          int vox = base + t * 16 + quad * 4 + r;
          __builtin_nontemporal_store(c[r], &y[(size_t)vox * COUT + co]);
          float v = c[r];
          if (h == 0) { s0 += v; q0 += v * v; }
          else        { s1 += v; q1 += v * v; }
        }
      }
    }
  }
  s0 += __shfl_xor(s0, 16); s0 += __shfl_xor(s0, 32);
  s1 += __shfl_xor(s1, 16); s1 += __shfl_xor(s1, 32);
  q0 += __shfl_xor(q0, 16); q0 += __shfl_xor(q0, 32);
  q1 += __shfl_xor(q1, 16); q1 += __shfl_xor(q1, 32);
  if (quad == 0) {
    smS[wave * 32 + col] = s0;
    smS[wave * 32 + 16 + col] = s1;
    smQ[wave * 32 + col] = q0;
    smQ[wave * 32 + 16 + col] = q1;
  }
  __syncthreads();
  int tid = threadIdx.x;
  if (tid < 64) {
    int co = tid & 31;
    const float* arr = (tid < 32) ? smS : smQ;
    float s = arr[co] + arr[32 + co] + arr[64 + co] + arr[96 + co];
    atomicAdd(&stats[(tid < 32 ? 0 : 32) + co], s);
  }
}

// BN finalize (per-block, from raw sums) + normalize + ReLU, in place, all NT.
__global__ void bn_apply(float* __restrict__ y, const float* __restrict__ stats,
                         const float* __restrict__ gamma,
                         const float* __restrict__ beta, int total4, float invN) {
  __shared__ float sc_sh[64];
  int tid = threadIdx.x;
  if (tid < 32) {
    float mean = stats[tid] * invN;
    float ex2 = stats[32 + tid] * invN;
    float var = ex2 - mean * mean;
    float inv = rsqrtf(var + EPSV);
    float sc = gamma[tid] * inv;
    sc_sh[tid] = sc;
    sc_sh[32 + tid] = beta[tid] - mean * sc;
  }
  __syncthreads();
  int t = blockIdx.x * blockDim.x + tid;
  if (t >= total4) return;
  size_t g = (size_t)t * 4;
  int co = (int)(g & 31);
  floatx4 v = __builtin_nontemporal_load((const floatx4*)(y + g));
  floatx4 sc = *(const floatx4*)&sc_sh[co];
  floatx4 sh = *(const floatx4*)&sc_sh[32 + co];
  floatx4 o;
#pragma unroll
  for (int j = 0; j < 4; ++j) o[j] = fmaxf(0.f, v[j] * sc[j] + sh[j]);
  __builtin_nontemporal_store(o, (floatx4*)(y + g));
}

extern "C" void kernel_launch(void* const* d_in, const int* in_sizes, int n_in,
                              void* d_out, int out_size, void* d_ws,
                              size_t ws_size, hipStream_t stream) {
  const float* feats = (const float*)d_in[0];
  const float* W = (const float*)d_in[1];
  const float* gamma = (const float*)d_in[2];
  const float* beta = (const float*)d_in[3];
  const int* nidx = (const int*)d_in[4];
  const unsigned char* nmask = (const unsigned char*)d_in[5];
  float* out = (float*)d_out;

  int N = in_sizes[0] / CIN;  // 1,000,000

  char* ws = (char*)d_ws;
  size_t f16_bytes = (size_t)N * CIN * sizeof(_Float16);
  _Float16* f16 = (_Float16*)ws;
  _Float16* wp = (_Float16*)(ws + f16_bytes);
  size_t wp_bytes = (size_t)KOFF * 2 * 64 * 8 * sizeof(_Float16);
  size_t stats_off = ((f16_bytes + wp_bytes + 511) / 512) * 512;
  float* stats = (float*)(ws + stats_off);
  int* flag = (int*)(stats + 64);
  size_t nbrT_off = ((stats_off + 768 + 255) / 256) * 256;
  int* nbrT = (int*)(ws + nbrT_off);

  hipMemsetAsync(stats, 0, 65 * sizeof(float), stream);

  setup_k<<<KOFF + 1, 128, 0, stream>>>(W, wp, nmask, flag);

  int total8 = N * CIN / 8;
  int cvtBlocks = (total8 + 255) / 256;
  int nbrBlocks = (N + 255) / 256;
  prep_k<<<cvtBlocks + nbrBlocks, 256, 0, stream>>>(feats, f16, total8, nidx,
                                                    nmask, flag, nbrT, N,
                                                    cvtBlocks);

  int nwaves = (N + 63) / 64;
  int nblocks = (nwaves + 3) / 4;
  conv_mfma_t<<<nblocks, 256, 0, stream>>>(f16, wp, nbrT, out, stats, N);

  int total4 = N * COUT / 4;
  bn_apply<<<(total4 + 255) / 256, 256, 0, stream>>>(out, stats, gamma, beta,
                                                     total4, 1.0f / (float)N);
}